// Round 9
// baseline (207.149 us; speedup 1.0000x reference)
//
#include <hip/hip_runtime.h>
#include <stdint.h>

#define ROWS   4096
#define NCOL   8192
#define TARGET 7680
#define NW     (NCOL - TARGET + 1)   // 513 windows
#define NT     512                   // threads per block (8 waves)
#define VPT    (NCOL / NT)           // 16 values per thread (in VGPRs)
#define NB     2048                  // histogram bins
#define BPT    (NB / NT)             // 4 bins per thread in scan
#define NWAVE  (NT / 64)             // 8 waves
#define SCAP   2048                  // sorted-buffer capacity (typ. tot ~1058)
#define MAXS   (SCAP / NT)           // max slots per thread in fixup (4)
#define FMN    (-16.0f)              // fixed bin range [-16,16): exact for any
#define FSC    ((float)NB / 32.0f)   // data (monotone map); fallback if tails
                                     // don't fit SCAP (never on N(0,1) rows)

struct Smem {
    uint32_t hist[NB];       // transposed: logical bin b at ((b&3)<<9)|(b>>2)
    float    sorted[SCAP];   // scattered candidates (unordered within bin)
    float    sorted2[SCAP];  // fixup output: exact sorted tails
    uint32_t wsum[NWAVE];
    uint32_t res[4];         // [0]=B_lo [1]=cntB(incl) [2]=B_hi [3]=topBase(excl)
    float    fmin[NWAVE], fmax[NWAVE];   // fallback path only
};

// Monotone clamped binning: exact rank-finding for ANY (mn, s); range only
// affects candidate-count efficiency, which the tot>SCAP fallback guards.
__device__ __forceinline__ int binf(float v, float mn, float s) {
    int b = (int)((v - mn) * s);
    b = b < 0 ? 0 : b;
    return b > NB - 1 ? NB - 1 : b;
}
// transposed physical index: scan reads hist[(j<<9)|tid] lane-consecutively
// (conflict-free); atomics hash on bin bits 2..6 (random for random values).
// (round-7: identity layout 2.4x'd bank conflicts -> keep transposed)
__device__ __forceinline__ int HIX(int b) { return ((b & 3) << 9) | (b >> 2); }

struct P1Out { int B_lo, B_hi; uint32_t cntB, topBase, shiftT, tot; };

// hist + scan + rank-locate. LOAD=true: fused global load -> bin -> atomic
// (loads overlap atomic issue; no min/max drain in front). LOAD=false
// (fallback): re-bin from registers with dynamic range.
template<bool LOAD>
__device__ __forceinline__ void phase1(Smem& sm, const float* __restrict__ xrow,
                                       float (&v)[VPT], uint32_t (&binPk)[VPT / 2],
                                       float mn, float sc,
                                       int tid, int lane, int wid, P1Out& o) {
    if (LOAD) {
        const float4* xv = (const float4*)xrow;
        #pragma unroll
        for (int q = 0; q < VPT / 4; q++) {
            float4 t = xv[tid + q * NT];
            v[4 * q + 0] = t.x; v[4 * q + 1] = t.y;
            v[4 * q + 2] = t.z; v[4 * q + 3] = t.w;
            int b0 = binf(t.x, mn, sc), b1 = binf(t.y, mn, sc);
            int b2 = binf(t.z, mn, sc), b3 = binf(t.w, mn, sc);
            binPk[2 * q + 0] = (uint32_t)b0 | ((uint32_t)b1 << 16);
            binPk[2 * q + 1] = (uint32_t)b2 | ((uint32_t)b3 << 16);
            atomicAdd(&sm.hist[HIX(b0)], 1u);
            atomicAdd(&sm.hist[HIX(b1)], 1u);
            atomicAdd(&sm.hist[HIX(b2)], 1u);
            atomicAdd(&sm.hist[HIX(b3)], 1u);
        }
    } else {
        #pragma unroll
        for (int j = 0; j < VPT; j += 2) {
            int b0 = binf(v[j],     mn, sc);
            int b1 = binf(v[j + 1], mn, sc);
            binPk[j >> 1] = (uint32_t)b0 | ((uint32_t)b1 << 16);
            atomicAdd(&sm.hist[HIX(b0)], 1u);
            atomicAdd(&sm.hist[HIX(b1)], 1u);
        }
    }
    __syncthreads();                                             // S2

    // ---- block scan of hist + locate rank bins + write scatter bases ----
    uint32_t h[BPT], s0 = 0;
    #pragma unroll
    for (int j = 0; j < BPT; j++) { h[j] = sm.hist[(j << 9) | tid]; s0 += h[j]; }
    uint32_t sc2 = s0;
    #pragma unroll
    for (int off = 1; off < 64; off <<= 1) {
        uint32_t n = __shfl_up(sc2, off, 64);
        if (lane >= off) sc2 += n;
    }
    if (lane == 63) sm.wsum[wid] = sc2;
    __syncthreads();                                             // S3
    uint32_t woff = 0;
    #pragma unroll
    for (int w = 0; w < NWAVE; w++) if (w < wid) woff += sm.wsum[w];
    const uint32_t incl = sc2 + woff, excl = incl - s0;
    const uint32_t ka = NW - 1, kb = TARGET - 1;
    if (ka >= excl && ka < incl) {           // bin of rank 512 (bottom tail end)
        uint32_t c = excl; bool done = false;
        #pragma unroll
        for (int j = 0; j < BPT; j++) {
            if (!done) {
                if (ka < c + h[j]) {
                    sm.res[0] = (uint32_t)(tid * BPT + j);
                    sm.res[1] = c + h[j];    // cntB = inclusive prefix at B_lo
                    done = true;
                } else c += h[j];
            }
        }
    }
    if (kb >= excl && kb < incl) {           // bin of rank 7679 (top tail start)
        uint32_t c = excl; bool done = false;
        #pragma unroll
        for (int j = 0; j < BPT; j++) {
            if (!done) {
                if (kb < c + h[j]) {
                    sm.res[2] = (uint32_t)(tid * BPT + j);
                    sm.res[3] = c;           // topBase = exclusive prefix at B_hi
                    done = true;
                } else c += h[j];
            }
        }
    }
    {   // overwrite counts with exclusive-prefix bases (independent of res)
        uint32_t run = excl;
        #pragma unroll
        for (int j = 0; j < BPT; j++) { sm.hist[(j << 9) | tid] = run; run += h[j]; }
    }
    __syncthreads();                                             // S4
    o.B_lo = (int)sm.res[0]; o.cntB    = sm.res[1];
    o.B_hi = (int)sm.res[2]; o.topBase = sm.res[3];
    o.shiftT = o.cntB - o.topBase;           // mod-2^32; top slot = excl + shiftT
    o.tot = o.cntB + (uint32_t)NCOL - o.topBase;   // UNCAPPED (overflow probe)
}

// NT=512 confirmed (round-8: NT=256 doubles per-thread state past what the
// allocator keeps live -> rematerialization, 84us). launch_bounds(512,4):
// 128-VGPR budget, no forced ceiling (round-3: forced 64 spilled). ~55 VGPR
// expected. 4 blocks/CU (wave-capped), grid 4096 for natural phase stagger
// (round-5: small-grid convoys lockstep and lose 2x).
__global__ __launch_bounds__(NT, 4)
void recall_window_kernel(const float* __restrict__ x, float* __restrict__ out) {
    __shared__ Smem sm;
    const int tid = threadIdx.x;
    const int row = blockIdx.x;
    const int lane = tid & 63, wid = tid >> 6;

    // ---- zero hist (one b128 store), cheap barrier: nothing in flight ----
    {
        uint4 z; z.x = 0; z.y = 0; z.z = 0; z.w = 0;
        *(uint4*)&sm.hist[tid * 4] = z;
    }
    __syncthreads();                                             // S1 (cheap)

    float    v[VPT];
    uint32_t binPk[VPT / 2];
    P1Out    o;
    phase1<true>(sm, x + (size_t)row * NCOL, v, binPk, FMN, FSC,
                 tid, lane, wid, o);

    if (o.tot > SCAP) {   // uniform rare path: fixed bins too coarse for this
        // row -> recompute with exact row range (exactness parity with the
        // old always-minmax kernel; never taken on Gaussian bench rows).
        float mn = v[0], mx = v[0];
        #pragma unroll
        for (int j = 1; j < VPT; j++) { mn = fminf(mn, v[j]); mx = fmaxf(mx, v[j]); }
        #pragma unroll
        for (int off = 32; off > 0; off >>= 1) {
            mn = fminf(mn, __shfl_down(mn, off, 64));
            mx = fmaxf(mx, __shfl_down(mx, off, 64));
        }
        if (lane == 0) { sm.fmin[wid] = mn; sm.fmax[wid] = mx; }
        {
            uint4 z; z.x = 0; z.y = 0; z.z = 0; z.w = 0;
            *(uint4*)&sm.hist[tid * 4] = z;          // re-zero for re-hist
        }
        __syncthreads();
        #pragma unroll
        for (int w = 0; w < NWAVE; w++) {
            mn = fminf(mn, sm.fmin[w]);
            mx = fmaxf(mx, sm.fmax[w]);
        }
        if (!(mx > mn)) {   // all values equal (uniform early-out)
            if (tid == 0) { out[row] = mn; out[ROWS + row] = mn; }
            return;
        }
        phase1<false>(sm, nullptr, v, binPk, mn, (float)NB / (mx - mn),
                      tid, lane, wid, o);
        if (o.tot > SCAP) o.tot = SCAP;   // dup-heavy worst case: same clamp
    }                                     // behavior as previous kernels
    const int      B_lo   = o.B_lo;
    const int      B_hi   = o.B_hi;
    const uint32_t cntB   = o.cntB, topBase = o.topBase, shiftT = o.shiftT;
    const uint32_t tot    = o.tot;
    const float    mnG    = FMN;  // NOTE: only used via binPk below; fixup
                                  // recomputes bins, so pass the scale used:
    // (fixup must re-bin with the SAME map as phase1; stash it)
    // -- determined by which path ran; recover from binPk instead: fixup
    //    needs bin(vv). We avoid recompute mismatch by deriving fixup bins
    //    from hist ranges only when needed; simplest correct: recompute with
    //    the active map. Track it explicitly:
    // (set below)

    // ---- Scatter candidates directly to global-rank slots (cached bins) ----
    #pragma unroll
    for (int j = 0; j < VPT; j++) {
        int b = (int)((binPk[j >> 1] >> ((j & 1) * 16)) & 0xffffu);
        if (b <= B_lo || b >= B_hi) {
            uint32_t pos = atomicAdd(&sm.hist[HIX(b)], 1u);
            if (b >= B_hi) pos += shiftT;
            if (pos < SCAP) sm.sorted[pos] = v[j];
        }
    }
    __syncthreads();                                             // S5
    // now hist[b] = exclusive prefix + count = inclusive end (unshifted, top)

    // ---- Fix-up: rank within bins, write to sorted2 (no WB hazard) ----
    // Bin of a staged value is recovered by range-locating it against the
    // prefix table instead of re-binning (map-independent): a slot s in
    // [hist[b-1], hist[b]) belongs to bin b. We know each value's bin only
    // via binPk for OUR OWN values; sorted[s] may be another thread's. So
    // recompute with the active map: both paths end with binPk built from
    // the same (mn,sc) as the final hist -- recompute using that map.
    {
        // Recover active map: if fallback ran, (mnA, scA) were its params.
        // We re-derive by checking which map binPk came from is unnecessary:
        // stash in shared would cost a barrier; instead recompute per path
        // was folded -- fixup below uses binary search over the prefix
        // table: locate b such that st<=s<en. Bottom side: bins 0..B_lo,
        // top side: bins B_hi..NB-1 (slots shifted by shiftT).
        #pragma unroll
        for (int it = 0; it < MAXS; it++) {
            int s = tid + it * NT;
            if (s < (int)tot) {
                float vv = sm.sorted[s];
                bool bot = s < (int)cntB;
                // binary search the owning bin over the monotone prefix arr
                int lo = bot ? 0 : B_hi, hi = bot ? B_lo : NB - 1;
                uint32_t su = bot ? (uint32_t)s : (uint32_t)s - shiftT;
                // find largest b in [lo,hi] with base(b) <= su, where
                // base(b) = (b==B_hi && !bot) ? topBase : hist[b-1] for b>0
                // hist[b] currently = inclusive end of bin b.
                while (lo < hi) {            // ~11 iterations max
                    int mid = (lo + hi) >> 1;
                    // inclusive end of bin mid:
                    uint32_t en_m = sm.hist[HIX(mid)];
                    if (su < en_m) hi = mid; else lo = mid + 1;
                }
                int b = lo;
                uint32_t en = sm.hist[HIX(b)];
                uint32_t st;
                if (bot) {
                    st = (b == 0) ? 0u : sm.hist[HIX(b - 1)];
                } else {
                    st = (b == B_hi) ? topBase : sm.hist[HIX(b - 1)];
                    st += shiftT; en += shiftT;
                }
                if (en > tot) en = tot;
                uint32_t r = 0;
                if (en - st > 1) {
                    for (uint32_t q = st; q < en; q++) {
                        float u = sm.sorted[q];
                        r += (u < vv) || (u == vv && (int)q < s);
                    }
                }
                uint32_t d = st + r;
                if (d < SCAP) sm.sorted2[d] = vv;
            }
        }
    }
    __syncthreads();                                             // S6

    // sorted2[0..cntB) = global ranks 0..cntB-1; sorted2[cntB..tot) = top tail.
    // window i: left = sorted2[i]; right = sorted2[tot - NW + i]

    // ---- single-wave argmin: wave 0 reduces 513 windows (9/lane) ----
    if (wid == 0) {
        const int topstart = (int)tot - NW;
        float lbest = __int_as_float(0x7F800000);   // +inf
        int   lidx  = 0x7FFFFFFF;
        for (int i = lane; i < NW; i += 64) {
            float len = sm.sorted2[topstart + i] - sm.sorted2[i];
            if (len < lbest) { lbest = len; lidx = i; }
        }
        #pragma unroll
        for (int off = 32; off > 0; off >>= 1) {
            float v2 = __shfl_down(lbest, off, 64);
            int   i2 = __shfl_down(lidx,  off, 64);
            if (v2 < lbest || (v2 == lbest && i2 < lidx)) { lbest = v2; lidx = i2; }
        }
        if (lane == 0) {
            out[row]        = sm.sorted2[lidx];             // left  = s[idx]
            out[ROWS + row] = sm.sorted2[topstart + lidx];  // right = s[idx+target-1]
        }
    }
    (void)mnG;
}

extern "C" void kernel_launch(void* const* d_in, const int* in_sizes, int n_in,
                              void* d_out, int out_size, void* d_ws, size_t ws_size,
                              hipStream_t stream) {
    const float* x = (const float*)d_in[0];
    float* out = (float*)d_out;
    recall_window_kernel<<<ROWS, NT, 0, stream>>>(x, out);
}

// Round 10
// 200.586 us; speedup vs baseline: 1.0327x; 1.0327x over previous
//
#include <hip/hip_runtime.h>
#include <stdint.h>

#define ROWS   4096
#define NCOL   8192
#define TARGET 7680
#define NW     (NCOL - TARGET + 1)   // 513 windows
#define NT     512                   // threads per block (8 waves)
#define VPT    (NCOL / NT)           // 16 values per thread (in VGPRs)
#define NB     2048                  // histogram bins
#define BPT    (NB / NT)             // 4 bins per thread in scan
#define NWAVE  (NT / 64)             // 8 waves
#define SCAP   2048                  // sorted-buffer capacity (typ. tot ~1040)
#define MAXS   (SCAP / NT)           // max slots per thread in fixup (4)
// Fixed bin map [-4,4): 256 bins/unit ~= round-6's dynamic ~227/unit -> same
// ~4-element tail bins (fixup cost unchanged). Outliers clamp to bins 0/2047;
// map stays monotone so ranks stay exact; tot>SCAP fallback guards pathology.
#define FMN    (-4.0f)
#define FSC    ((float)NB / 8.0f)

struct Smem {
    uint32_t hist[NB];       // transposed: logical bin b at ((b&3)<<9)|(b>>2)
    float    sorted[SCAP];   // scattered candidates (unordered within bin)
    float    sorted2[SCAP];  // fixup output: exact sorted tails
    uint32_t wsum[NWAVE];
    uint32_t res[4];         // [0]=B_lo [1]=cntB(incl) [2]=B_hi [3]=topBase(excl)
    float    fmin[NWAVE], fmax[NWAVE];   // fallback path only
};

// Monotone clamped binning: exact rank-partition for ANY (mn, s).
__device__ __forceinline__ int binf(float v, float mn, float s) {
    int b = (int)((v - mn) * s);
    b = b < 0 ? 0 : b;
    return b > NB - 1 ? NB - 1 : b;
}
// transposed physical index: scan reads hist[(j<<9)|tid] lane-consecutively
// (conflict-free); atomics hash on bin bits 2..6 (random for random values).
// (round-7: identity layout 2.4x'd bank conflicts -> keep transposed)
__device__ __forceinline__ int HIX(int b) { return ((b & 3) << 9) | (b >> 2); }

struct P1Out { int B_lo, B_hi; uint32_t cntB, topBase, shiftT, tot; };

// hist + scan + rank-locate. LOAD=true: fused global load -> bin -> atomic
// (each chunk's atomics wait only on its own load -> loads overlap atomic
// issue; no min/max vmcnt(0) drain in front). LOAD=false (fallback): re-bin
// from registers with the dynamic row range.
template<bool LOAD>
__device__ __forceinline__ void phase1(Smem& sm, const float* __restrict__ xrow,
                                       float (&v)[VPT], uint32_t (&binPk)[VPT / 2],
                                       float mn, float sc,
                                       int tid, int lane, int wid, P1Out& o) {
    if (LOAD) {
        const float4* xv = (const float4*)xrow;
        #pragma unroll
        for (int q = 0; q < VPT / 4; q++) {
            float4 t = xv[tid + q * NT];
            v[4 * q + 0] = t.x; v[4 * q + 1] = t.y;
            v[4 * q + 2] = t.z; v[4 * q + 3] = t.w;
            int b0 = binf(t.x, mn, sc), b1 = binf(t.y, mn, sc);
            int b2 = binf(t.z, mn, sc), b3 = binf(t.w, mn, sc);
            binPk[2 * q + 0] = (uint32_t)b0 | ((uint32_t)b1 << 16);
            binPk[2 * q + 1] = (uint32_t)b2 | ((uint32_t)b3 << 16);
            atomicAdd(&sm.hist[HIX(b0)], 1u);
            atomicAdd(&sm.hist[HIX(b1)], 1u);
            atomicAdd(&sm.hist[HIX(b2)], 1u);
            atomicAdd(&sm.hist[HIX(b3)], 1u);
        }
    } else {
        #pragma unroll
        for (int j = 0; j < VPT; j += 2) {
            int b0 = binf(v[j],     mn, sc);
            int b1 = binf(v[j + 1], mn, sc);
            binPk[j >> 1] = (uint32_t)b0 | ((uint32_t)b1 << 16);
            atomicAdd(&sm.hist[HIX(b0)], 1u);
            atomicAdd(&sm.hist[HIX(b1)], 1u);
        }
    }
    __syncthreads();                                             // S2

    // ---- block scan of hist + locate rank bins + write scatter bases ----
    uint32_t h[BPT], s0 = 0;
    #pragma unroll
    for (int j = 0; j < BPT; j++) { h[j] = sm.hist[(j << 9) | tid]; s0 += h[j]; }
    uint32_t sc2 = s0;
    #pragma unroll
    for (int off = 1; off < 64; off <<= 1) {
        uint32_t n = __shfl_up(sc2, off, 64);
        if (lane >= off) sc2 += n;
    }
    if (lane == 63) sm.wsum[wid] = sc2;
    __syncthreads();                                             // S3
    uint32_t woff = 0;
    #pragma unroll
    for (int w = 0; w < NWAVE; w++) if (w < wid) woff += sm.wsum[w];
    const uint32_t incl = sc2 + woff, excl = incl - s0;
    const uint32_t ka = NW - 1, kb = TARGET - 1;
    if (ka >= excl && ka < incl) {           // bin of rank 512 (bottom tail end)
        uint32_t c = excl; bool done = false;
        #pragma unroll
        for (int j = 0; j < BPT; j++) {
            if (!done) {
                if (ka < c + h[j]) {
                    sm.res[0] = (uint32_t)(tid * BPT + j);
                    sm.res[1] = c + h[j];    // cntB = inclusive prefix at B_lo
                    done = true;
                } else c += h[j];
            }
        }
    }
    if (kb >= excl && kb < incl) {           // bin of rank 7679 (top tail start)
        uint32_t c = excl; bool done = false;
        #pragma unroll
        for (int j = 0; j < BPT; j++) {
            if (!done) {
                if (kb < c + h[j]) {
                    sm.res[2] = (uint32_t)(tid * BPT + j);
                    sm.res[3] = c;           // topBase = exclusive prefix at B_hi
                    done = true;
                } else c += h[j];
            }
        }
    }
    {   // overwrite counts with exclusive-prefix bases (independent of res)
        uint32_t run = excl;
        #pragma unroll
        for (int j = 0; j < BPT; j++) { sm.hist[(j << 9) | tid] = run; run += h[j]; }
    }
    __syncthreads();                                             // S4
    o.B_lo = (int)sm.res[0]; o.cntB    = sm.res[1];
    o.B_hi = (int)sm.res[2]; o.topBase = sm.res[3];
    o.shiftT = o.cntB - o.topBase;           // mod-2^32; top slot = excl + shiftT
    o.tot = o.cntB + (uint32_t)NCOL - o.topBase;   // UNCAPPED (overflow probe)
}

// NT=512 confirmed (round-8: NT=256's 48-word per-thread state thrashes the
// allocator). launch_bounds(512,4): 128-VGPR budget, no forced ceiling
// (round-3: forced 64 spilled). Grid 4096, one row/block: natural phase
// stagger across blocks (round-5: small-grid convoys lockstep and lose 2x).
__global__ __launch_bounds__(NT, 4)
void recall_window_kernel(const float* __restrict__ x, float* __restrict__ out) {
    __shared__ Smem sm;
    const int tid = threadIdx.x;
    const int row = blockIdx.x;
    const int lane = tid & 63, wid = tid >> 6;

    // ---- zero hist (one b128 store), cheap barrier: nothing in flight ----
    {
        uint4 z; z.x = 0; z.y = 0; z.z = 0; z.w = 0;
        *(uint4*)&sm.hist[tid * 4] = z;
    }
    __syncthreads();                                             // S1 (cheap)

    float    v[VPT];
    uint32_t binPk[VPT / 2];
    P1Out    o;
    float    amn = FMN, asc = FSC;           // active bin map (block-uniform)
    phase1<true>(sm, x + (size_t)row * NCOL, v, binPk, FMN, FSC,
                 tid, lane, wid, o);

    if (o.tot > SCAP) {   // uniform rare path: fixed map too coarse for this
        // row -> recompute with exact row range (never taken on bench rows).
        float mn = v[0], mx = v[0];
        #pragma unroll
        for (int j = 1; j < VPT; j++) { mn = fminf(mn, v[j]); mx = fmaxf(mx, v[j]); }
        #pragma unroll
        for (int off = 32; off > 0; off >>= 1) {
            mn = fminf(mn, __shfl_down(mn, off, 64));
            mx = fmaxf(mx, __shfl_down(mx, off, 64));
        }
        if (lane == 0) { sm.fmin[wid] = mn; sm.fmax[wid] = mx; }
        {
            uint4 z; z.x = 0; z.y = 0; z.z = 0; z.w = 0;
            *(uint4*)&sm.hist[tid * 4] = z;          // re-zero for re-hist
        }
        __syncthreads();
        #pragma unroll
        for (int w = 0; w < NWAVE; w++) {
            mn = fminf(mn, sm.fmin[w]);
            mx = fmaxf(mx, sm.fmax[w]);
        }
        if (!(mx > mn)) {   // all values equal (uniform early-out)
            if (tid == 0) { out[row] = mn; out[ROWS + row] = mn; }
            return;
        }
        amn = mn; asc = (float)NB / (mx - mn);
        phase1<false>(sm, nullptr, v, binPk, amn, asc, tid, lane, wid, o);
        if (o.tot > SCAP) o.tot = SCAP;   // dup-heavy worst case: same clamp
    }                                     // behavior as previous kernels
    const int      B_lo   = o.B_lo;
    const int      B_hi   = o.B_hi;
    const uint32_t cntB   = o.cntB, topBase = o.topBase, shiftT = o.shiftT;
    const uint32_t tot    = o.tot;

    // ---- Scatter candidates directly to global-rank slots (cached bins) ----
    #pragma unroll
    for (int j = 0; j < VPT; j++) {
        int b = (int)((binPk[j >> 1] >> ((j & 1) * 16)) & 0xffffu);
        if (b <= B_lo || b >= B_hi) {
            uint32_t pos = atomicAdd(&sm.hist[HIX(b)], 1u);
            if (b >= B_hi) pos += shiftT;
            if (pos < SCAP) sm.sorted[pos] = v[j];
        }
    }
    __syncthreads();                                             // S5
    // now hist[b] = exclusive prefix + count = inclusive end (unshifted, top)

    // ---- Fix-up: rank within bins via direct re-bin with the ACTIVE map
    //      (round-9's binary search was 11 dependent LDS reads -- removed) ----
    #pragma unroll
    for (int it = 0; it < MAXS; it++) {
        int s = tid + it * NT;
        if (s < (int)tot) {
            float vv = sm.sorted[s];
            int b = binf(vv, amn, asc);
            uint32_t en = sm.hist[HIX(b)];
            uint32_t st;
            if (s < (int)cntB) {
                st = (b == 0) ? 0u : sm.hist[HIX(b - 1)];
            } else {
                st = (b == B_hi) ? topBase : sm.hist[HIX(b - 1)];
                st += shiftT; en += shiftT;
            }
            if (en > tot) en = tot;
            uint32_t r = 0;
            if (en - st > 1) {
                for (uint32_t q = st; q < en; q++) {
                    float u = sm.sorted[q];
                    r += (u < vv) || (u == vv && (int)q < s);
                }
            }
            uint32_t d = st + r;
            if (d < SCAP) sm.sorted2[d] = vv;
        }
    }
    __syncthreads();                                             // S6

    // sorted2[0..cntB) = global ranks 0..cntB-1; sorted2[cntB..tot) = top tail.
    // window i: left = sorted2[i]; right = sorted2[tot - NW + i]

    // ---- single-wave argmin: wave 0 reduces 513 windows (9/lane) ----
    if (wid == 0) {
        const int topstart = (int)tot - NW;
        float lbest = __int_as_float(0x7F800000);   // +inf
        int   lidx  = 0x7FFFFFFF;
        for (int i = lane; i < NW; i += 64) {
            float len = sm.sorted2[topstart + i] - sm.sorted2[i];
            if (len < lbest) { lbest = len; lidx = i; }
        }
        #pragma unroll
        for (int off = 32; off > 0; off >>= 1) {
            float v2 = __shfl_down(lbest, off, 64);
            int   i2 = __shfl_down(lidx,  off, 64);
            if (v2 < lbest || (v2 == lbest && i2 < lidx)) { lbest = v2; lidx = i2; }
        }
        if (lane == 0) {
            out[row]        = sm.sorted2[lidx];             // left  = s[idx]
            out[ROWS + row] = sm.sorted2[topstart + lidx];  // right = s[idx+target-1]
        }
    }
}

extern "C" void kernel_launch(void* const* d_in, const int* in_sizes, int n_in,
                              void* d_out, int out_size, void* d_ws, size_t ws_size,
                              hipStream_t stream) {
    const float* x = (const float*)d_in[0];
    float* out = (float*)d_out;
    recall_window_kernel<<<ROWS, NT, 0, stream>>>(x, out);
}